// Round 4
// baseline (405.444 us; speedup 1.0000x reference)
//
#include <hip/hip_runtime.h>
#include <hip/hip_bf16.h>
#include <cstdint>

#define Bsz 32
#define Dd 2048
#define Ff 512

typedef __attribute__((ext_vector_type(8))) short short8;
typedef __attribute__((ext_vector_type(4))) float floatx4;

__device__ inline unsigned short f2bf(float f) {
  union { float f; unsigned int u; } c; c.f = f;
  unsigned int u = c.u;
  return (unsigned short)((u + 0x7FFFu + ((u >> 16) & 1u)) >> 16);
}

__device__ inline void gld_lds16(const void* g, void* l) {
  __builtin_amdgcn_global_load_lds(
      (const __attribute__((address_space(1))) void*)g,
      (__attribute__((address_space(3))) void*)l,
      16, 0, 0);
}

// K1: abs_sum[j] = sum_k |s[j] - s[k]|.
__global__ __launch_bounds__(256) void k_prep(const float* __restrict__ s,
                                              float* __restrict__ abs_sum) {
  __shared__ float sk[256];
  int t = threadIdx.x;
  int j = blockIdx.x * 256 + t;
  float sj = s[j];
  float acc = 0.f;
  for (int c = 0; c < Dd; c += 256) {
    __syncthreads();
    sk[t] = s[c + t];
    __syncthreads();
#pragma unroll 16
    for (int k = 0; k < 256; ++k) acc += fabsf(sj - sk[k]);
  }
  abs_sum[j] = acc;
}

// K2: per P-row i: softmax stats m_i, inv_i. One wave per row.
__global__ __launch_bounds__(256) void k_rowstats(const float* __restrict__ s,
                                                  const float* __restrict__ abs_sum,
                                                  float* __restrict__ mrow,
                                                  float* __restrict__ inv) {
  int w = threadIdx.x >> 6, l = threadIdx.x & 63;
  int i = blockIdx.x * 4 + w;
  float scal = 2047.0f - 2.0f * (float)i;  // D+1-2*(i+1)
  float v[32];
  float vmax = -3.4e38f;
#pragma unroll
  for (int it = 0; it < 32; ++it) {
    int j = it * 64 + l;
    v[it] = fmaf(scal, s[j], -abs_sum[j]);
    vmax = fmaxf(vmax, v[it]);
  }
#pragma unroll
  for (int off = 32; off > 0; off >>= 1) vmax = fmaxf(vmax, __shfl_xor(vmax, off, 64));
  float sum = 0.f;
#pragma unroll
  for (int it = 0; it < 32; ++it) sum += __expf(v[it] - vmax);
#pragma unroll
  for (int off = 32; off > 0; off >>= 1) sum += __shfl_xor(sum, off, 64);
  if (l == 0) { mrow[i] = vmax; inv[i] = 1.0f / sum; }
}

// K3: PT[j][d] = exp(scal_d*s_j - abs_sum_j - m_d) * inv_d (bf16), uint2 stores.
__global__ __launch_bounds__(256) void k_pt(const float* __restrict__ s,
                                            const float* __restrict__ abs_sum,
                                            const float* __restrict__ mrow,
                                            const float* __restrict__ inv,
                                            uint2* __restrict__ PTw) {
  int j = blockIdx.y;
  int d0 = (blockIdx.x * 256 + threadIdx.x) * 4;
  float sj = s[j], asj = abs_sum[j];
  float4 mv = *(const float4*)&mrow[d0];
  float4 iv = *(const float4*)&inv[d0];
  float sc0 = 2047.0f - 2.0f * (float)d0;
  float base = fmaf(sc0, sj, -asj);
  float step = -2.0f * sj;
  float p0 = __expf(base - mv.x) * iv.x;
  float p1 = __expf(base + step - mv.y) * iv.y;
  float p2 = __expf(base + 2.f * step - mv.z) * iv.z;
  float p3 = __expf(base + 3.f * step - mv.w) * iv.w;
  uint2 v;
  v.x = (unsigned int)f2bf(p0) | ((unsigned int)f2bf(p1) << 16);
  v.y = (unsigned int)f2bf(p2) | ((unsigned int)f2bf(p3) << 16);
  PTw[((size_t)j * Dd + d0) >> 2] = v;
}

// K4: XT[b][f][d] = bf16(x[b][d][f]). 64x64 tile; all-wide LDS:
// phase1 packs 4 consecutive d per lane -> ds_write_b64; phase2 ds_read_b128
// (144-B padded rows, 16-B aligned) -> uint4 stores in 64-B segments.
__global__ __launch_bounds__(256) void k_xt(const float* __restrict__ x,
                                            unsigned short* __restrict__ XT) {
  __shared__ unsigned short tt[64][72];  // 144-B stride, 16-B aligned
  int t = threadIdx.x;
  int w = t >> 6, l = t & 63;
  int d0 = blockIdx.x * 64, f0 = blockIdx.y * 64;
  const float* xb = x + (size_t)blockIdx.z * Dd * Ff + f0 + l;
#pragma unroll
  for (int k = 0; k < 4; ++k) {
    int ds = w * 4 + k * 16;  // d_start within tile
    float v0 = xb[(size_t)(d0 + ds) * Ff];
    float v1 = xb[(size_t)(d0 + ds + 1) * Ff];
    float v2 = xb[(size_t)(d0 + ds + 2) * Ff];
    float v3 = xb[(size_t)(d0 + ds + 3) * Ff];
    uint2 p;
    p.x = (unsigned int)f2bf(v0) | ((unsigned int)f2bf(v1) << 16);
    p.y = (unsigned int)f2bf(v2) | ((unsigned int)f2bf(v3) << 16);
    *(uint2*)&tt[l][ds] = p;
  }
  __syncthreads();
  unsigned short* xtb = XT + (size_t)blockIdx.z * Ff * Dd;
  int f = t >> 2, dc = t & 3;
#pragma unroll
  for (int j = 0; j < 2; ++j) {
    int doff = dc * 8 + j * 32;
    uint4 v = *(const uint4*)&tt[f][doff];
    *(uint4*)&xtb[(size_t)(f0 + f) * Dd + d0 + doff] = v;
  }
}

// K5: batched GEMM. C[b][m][n] = sum_k PT[m][k] * XT[b][n][k].
// 128x128 tile, BK=64, gld_lds w=16, XOR-source-swizzled LDS (2-way, free).
#define BM 128
#define BN 128
#define BK 64

__global__ __launch_bounds__(256) void k_gemm(const unsigned short* __restrict__ PT,
                                              const unsigned short* __restrict__ XT,
                                              float* __restrict__ out) {
  __shared__ unsigned short As[BM * BK];  // 16 KB
  __shared__ unsigned short Bs[BN * BK];  // 16 KB
  int t = threadIdx.x;

  // swizzle: 128 consecutive blocks share one PT slab (512 KB, L2-hot)
  int id = blockIdx.x;
  int mt = id >> 7;
  int rem = id & 127;
  int bz = rem >> 2;
  int nt = rem & 3;
  int m0 = mt * BM;
  int n0 = nt * BN;
  const unsigned short* Bsrc = XT + (size_t)bz * Ff * Dd;
  float* Cb = out + (size_t)bz * Dd * Ff;

  int l = t & 63, w = t >> 6;
  int wm = (w & 1) * 64, wn = (w >> 1) * 64;
  int lm = l & 15, lq = l >> 4;
  int sw = lm & 7;  // fragment-row swizzle key

  floatx4 acc[4][4];
#pragma unroll
  for (int i = 0; i < 4; ++i)
#pragma unroll
    for (int j = 0; j < 4; ++j) acc[i][j] = {0.f, 0.f, 0.f, 0.f};

  for (int k0 = 0; k0 < Dd; k0 += BK) {
    __syncthreads();
#pragma unroll
    for (int q = 0; q < 4; ++q) {
      int c = t + q * 256;               // LDS 16-B chunk index
      int row = c >> 3;
      int k16 = (c & 7) ^ (row & 7);     // source-swizzled k-chunk
      gld_lds16(PT + (size_t)(m0 + row) * Dd + k0 + k16 * 8, &As[c * 8]);
      gld_lds16(Bsrc + (size_t)(n0 + row) * Dd + k0 + k16 * 8, &Bs[c * 8]);
    }
    __syncthreads();

#pragma unroll
    for (int h = 0; h < 2; ++h) {
      int kc = h * 4 + lq;
      short8 a[4], b[4];
#pragma unroll
      for (int mi = 0; mi < 4; ++mi) {
        int row = wm + mi * 16 + lm;
        a[mi] = *(const short8*)&As[(row * 8 + (kc ^ sw)) * 8];
      }
#pragma unroll
      for (int ni = 0; ni < 4; ++ni) {
        int row = wn + ni * 16 + lm;
        b[ni] = *(const short8*)&Bs[(row * 8 + (kc ^ sw)) * 8];
      }
#pragma unroll
      for (int mi = 0; mi < 4; ++mi)
#pragma unroll
        for (int ni = 0; ni < 4; ++ni)
          acc[mi][ni] = __builtin_amdgcn_mfma_f32_16x16x32_bf16(a[mi], b[ni], acc[mi][ni], 0, 0, 0);
    }
  }

  // epilogue: C/D layout col=lane&15, row=(lane>>4)*4+reg (m89-verified)
#pragma unroll
  for (int mi = 0; mi < 4; ++mi) {
#pragma unroll
    for (int r = 0; r < 4; ++r) {
      int row = m0 + wm + mi * 16 + lq * 4 + r;
#pragma unroll
      for (int ni = 0; ni < 4; ++ni) {
        int col = n0 + wn + ni * 16 + lm;
        Cb[(size_t)row * Ff + col] = acc[mi][ni][r];
      }
    }
  }
}

extern "C" void kernel_launch(void* const* d_in, const int* in_sizes, int n_in,
                              void* d_out, int out_size, void* d_ws, size_t ws_size,
                              hipStream_t stream) {
  const float* x = (const float*)d_in[0];
  const float* s = (const float*)d_in[1];
  float* out = (float*)d_out;

  char* ws = (char*)d_ws;
  float* abs_sum = (float*)ws;                                   // 8 KB
  float* mrow = (float*)(ws + 8192);                             // 8 KB
  float* inv = (float*)(ws + 16384);                             // 8 KB
  unsigned short* PT = (unsigned short*)(ws + 24576);            // 8 MB
  unsigned short* XT = (unsigned short*)(ws + 24576 + 8388608);  // 64 MB

  k_prep<<<Dd / 256, 256, 0, stream>>>(s, abs_sum);
  k_rowstats<<<Dd / 4, 256, 0, stream>>>(s, abs_sum, mrow, inv);
  k_pt<<<dim3(Dd / 1024, Dd), 256, 0, stream>>>(s, abs_sum, mrow, inv, (uint2*)PT);
  k_xt<<<dim3(Dd / 64, Ff / 64, Bsz), 256, 0, stream>>>(x, XT);
  k_gemm<<<(Dd / BM) * (Ff / BN) * Bsz, 256, 0, stream>>>(PT, XT, out);
}